// Round 3
// baseline (179.761 us; speedup 1.0000x reference)
//
#include <hip/hip_runtime.h>

// RandomCutout: B=32, H=512, W=512, C=3 fp32, 2 masks of 128x128 per image.
// out[b,y,x,c] = in[b,y,x,c] unless (y,x) in any clipped mask rect, else 0.
//
// Geometry (m13 copy-bench shape): grid = 2048 blocks (8/CU) x 384 threads
// (6 waves). Each block owns 8 complete rows of one image (8 x 384 float4).
// Each thread handles the SAME flat column offset in all 8 rows -> 8
// independent global loads in flight per thread (128 B/lane) before any
// store; column cut-predicates computed ONCE, reused for all rows. b and
// the 8 row indices are block-uniform -> scalar center loads, uniform
// per-row branches.
//
// Column test, no divides: cut columns [x1,x2) <=> flat float offset
// p in [3*(cx-64), 3*(cx+64)) exactly (p = 3*xc + c, c in {0,1,2}).
//
// Output is write-once dead data (re-poisoned by the harness every
// iteration): stream it past the LLC with nontemporal stores so it cannot
// evict the input. NOTE: __builtin_nontemporal_store requires a native
// vector type, not HIP_vector_type -> use ext_vector_type(4) throughout.

#define BB 32
#define HH 512
#define ROW4 384          // float4 per row: 512*3/4
#define HALF 64           // MASK/2
#define RPB 8             // rows per block
#define TPB 384           // threads per block (= ROW4), 6 waves

typedef float f32x4 __attribute__((ext_vector_type(4)));

__global__ __launch_bounds__(TPB)
void RandomCutout_59545426592097_kernel(const f32x4* __restrict__ in,
                                        const int* __restrict__ cys,
                                        const int* __restrict__ cxs,
                                        f32x4* __restrict__ out) {
    const int blk = blockIdx.x;           // [0, 2048)
    const int b   = blk >> 6;             // 64 blocks per image  (uniform)
    const int y0  = (blk & 63) << 3;      // first of 8 rows      (uniform)
    const int t   = threadIdx.x;          // [0, 384)

    const int base = (b * HH + y0) * ROW4;
    const f32x4* __restrict__ src = in + base;
    f32x4* __restrict__ dst       = out + base;

    // 8 independent loads in flight (full MLP depth before any store).
    f32x4 v[RPB];
#pragma unroll
    for (int r = 0; r < RPB; ++r) v[r] = src[r * ROW4 + t];

    // Uniform per-image mask parameters (scalar loads).
    const int cy0 = cys[2 * b + 0];
    const int cy1 = cys[2 * b + 1];
    const int cx0 = cxs[2 * b + 0];
    const int cx1 = cxs[2 * b + 1];

    // Column intervals in flat float offsets (unclipped == clipped in-range).
    const int A1 = 3 * (cx0 - HALF), A2 = 3 * (cx0 + HALF);
    const int B1 = 3 * (cx1 - HALF), B2 = 3 * (cx1 + HALF);

    // Per-thread column membership for the 4 floats — computed once,
    // reused across all 8 rows (same flat offset every row).
    const int p = t * 4;
    const bool a0 = (p + 0 >= A1) & (p + 0 < A2);
    const bool a1 = (p + 1 >= A1) & (p + 1 < A2);
    const bool a2 = (p + 2 >= A1) & (p + 2 < A2);
    const bool a3 = (p + 3 >= A1) & (p + 3 < A2);
    const bool b0 = (p + 0 >= B1) & (p + 0 < B2);
    const bool b1 = (p + 1 >= B1) & (p + 1 < B2);
    const bool b2 = (p + 2 >= B1) & (p + 2 < B2);
    const bool b3 = (p + 3 >= B1) & (p + 3 < B2);

#pragma unroll
    for (int r = 0; r < RPB; ++r) {
        const int y = y0 + r;
        const bool ya = (y >= cy0 - HALF) & (y < cy0 + HALF);  // uniform
        const bool yb = (y >= cy1 - HALF) & (y < cy1 + HALF);  // uniform
        if (ya | yb) {                    // uniform branch per row
            if ((ya & a0) | (yb & b0)) v[r].x = 0.0f;
            if ((ya & a1) | (yb & b1)) v[r].y = 0.0f;
            if ((ya & a2) | (yb & b2)) v[r].z = 0.0f;
            if ((ya & a3) | (yb & b3)) v[r].w = 0.0f;
        }
        __builtin_nontemporal_store(v[r], &dst[r * ROW4 + t]);
    }
}

extern "C" void kernel_launch(void* const* d_in, const int* in_sizes, int n_in,
                              void* d_out, int out_size, void* d_ws, size_t ws_size,
                              hipStream_t stream) {
    const f32x4* in  = (const f32x4*)d_in[0];
    const int*   cys = (const int*)d_in[1];
    const int*   cxs = (const int*)d_in[2];
    f32x4*       out = (f32x4*)d_out;

    const int blocks = BB * (HH / RPB);   // 2048 blocks, 8 rows each
    RandomCutout_59545426592097_kernel<<<blocks, TPB, 0, stream>>>(in, cys, cxs, out);
}

// Round 4
// 173.652 us; speedup vs baseline: 1.0352x; 1.0352x over previous
//
#include <hip/hip_runtime.h>

// RandomCutout: B=32, H=512, W=512, C=3 fp32, 2 masks of 128x128 per image.
// out[b,y,x,c] = in[b,y,x,c] unless (y,x) in any clipped mask rect, else 0.
//
// Round-0 geometry (best observed: ~54 us): 256-thread blocks, exactly one
// float4 per thread, exact grid (24576 blocks). Three shape variants (wave
// churn, MLP depth 8, nt-stores) all landed 54-61 us with identical
// FETCH_SIZE -> the regime is externally capped; micro-structure is not the
// lever. The one remaining real lever is TRAFFIC: float4s that are fully
// inside a cut rectangle (~12.6 MB of the 96 MiB input) need no read at
// all - predicate first, load under the exec mask. Cut interiors are
// contiguous (96 float4/row), so masked lanes cover whole 128B lines and
// the fetch genuinely disappears.
//
// Column test, no divides for the cut check: cut columns [x1,x2) <=> flat
// float offset p in [3*(cx-64), 3*(cx+64)) exactly (p = 3*xc + c). Unclipped
// bounds are equivalent to clipped within p in [0,1536), y in [0,512).

#define BB 32
#define HH 512
#define WW 512
#define ROW4 384                 // float4 per row: 512*3/4
#define PER_IMG4 196608          // float4 per image
#define TOTAL4 (BB * PER_IMG4)   // 6,291,456
#define HALF 64                  // MASK/2

__global__ __launch_bounds__(256)
void RandomCutout_59545426592097_kernel(const float4* __restrict__ in,
                                        const int* __restrict__ cys,
                                        const int* __restrict__ cxs,
                                        float4* __restrict__ out) {
    const int g   = blockIdx.x * 256 + threadIdx.x;   // < TOTAL4, exact grid
    const int b   = g / PER_IMG4;
    const int rem = g - b * PER_IMG4;
    const int y   = rem / ROW4;
    const int p   = (rem - y * ROW4) * 4;  // flat float offset in row [0,1536)

    // Per-image mask parameters.
    const int cy0 = cys[2 * b + 0], cy1 = cys[2 * b + 1];
    const int cx0 = cxs[2 * b + 0], cx1 = cxs[2 * b + 1];
    const bool ya = (y >= cy0 - HALF) & (y < cy0 + HALF);
    const bool yb = (y >= cy1 - HALF) & (y < cy1 + HALF);
    const int A1 = 3 * (cx0 - HALF), A2 = 3 * (cx0 + HALF);
    const int B1 = 3 * (cx1 - HALF), B2 = 3 * (cx1 + HALF);

    // Per-float cut predicates.
    const bool c0 = (ya & (p + 0 >= A1) & (p + 0 < A2)) | (yb & (p + 0 >= B1) & (p + 0 < B2));
    const bool c1 = (ya & (p + 1 >= A1) & (p + 1 < A2)) | (yb & (p + 1 >= B1) & (p + 1 < B2));
    const bool c2 = (ya & (p + 2 >= A1) & (p + 2 < A2)) | (yb & (p + 2 >= B1) & (p + 2 < B2));
    const bool c3 = (ya & (p + 3 >= A1) & (p + 3 < A2)) | (yb & (p + 3 >= B1) & (p + 3 < B2));

    float4 v = make_float4(0.0f, 0.0f, 0.0f, 0.0f);
    if (!(c0 & c1 & c2 & c3)) {          // fully-cut float4s: skip the read
        v = in[g];
        if (c0) v.x = 0.0f;
        if (c1) v.y = 0.0f;
        if (c2) v.z = 0.0f;
        if (c3) v.w = 0.0f;
    }
    out[g] = v;
}

extern "C" void kernel_launch(void* const* d_in, const int* in_sizes, int n_in,
                              void* d_out, int out_size, void* d_ws, size_t ws_size,
                              hipStream_t stream) {
    const float4* in  = (const float4*)d_in[0];
    const int*    cys = (const int*)d_in[1];
    const int*    cxs = (const int*)d_in[2];
    float4*       out = (float4*)d_out;

    const int threads = 256;
    const int blocks  = TOTAL4 / threads;   // 24576, exact
    RandomCutout_59545426592097_kernel<<<blocks, threads, 0, stream>>>(in, cys, cxs, out);
}